// Round 2
// baseline (887.832 us; speedup 1.0000x reference)
//
#include <hip/hip_runtime.h>
#include <hip/hip_bf16.h>
#include <math.h>

// Problem constants (B=4, S=2048, Hd=1024, h=16, d=64). fp32 in/out per the
// reference; bf16 internally (MFMA) with fp32 accumulation.
#define B_SZ   4
#define S_LEN  2048
#define HD     1024
#define NHEAD  16
#define DHEAD  64
#define N3     3072          // 3*Hd
#define M_ROWS 8192          // B*S

typedef __bf16 bf16_t;
typedef __bf16 bf16x8 __attribute__((ext_vector_type(8)));
typedef float  floatx4 __attribute__((ext_vector_type(4)));

typedef __attribute__((address_space(1))) void gv_t;   // global
typedef __attribute__((address_space(3))) void lv_t;   // LDS

__device__ __forceinline__ float bf2f(bf16_t x) { return (float)x; }
__device__ __forceinline__ bf16_t f2bf(float f) { return (bf16_t)f; }  // RNE fptrunc

__device__ __forceinline__ bf16x8 cvt8(const float* __restrict__ p) {
    float4 lo = *(const float4*)(p);
    float4 hi = *(const float4*)(p + 4);
    bf16x8 r;
    r[0] = (bf16_t)lo.x; r[1] = (bf16_t)lo.y; r[2] = (bf16_t)lo.z; r[3] = (bf16_t)lo.w;
    r[4] = (bf16_t)hi.x; r[5] = (bf16_t)hi.y; r[6] = (bf16_t)hi.z; r[7] = (bf16_t)hi.w;
    return r;
}

// ---------------------------------------------------------------------------
// Kernel 1: qkv = X @ W^T + b (fp32 in, bf16 MFMA, fp32 acc), fused RoPE on
// q,k; scatter bf16 to [b][h][s][d] workspace.
// 128x128 tile, BK=32, global_load_lds width=16 (4 floats/lane), 2x2 waves,
// each wave 4x4 of 16x16x32 MFMA tiles. Wave column span is 64-aligned so the
// RoPE pair (dim, dim+32) lives in the same lane: acc n-tiles j and j+2.
// ---------------------------------------------------------------------------
__global__ __launch_bounds__(256, 2)
void qkv_rope_kernel(const float* __restrict__ X, const float* __restrict__ W,
                     const float* __restrict__ bias,
                     bf16_t* __restrict__ qws, bf16_t* __restrict__ kws,
                     bf16_t* __restrict__ vws)
{
    __shared__ float As[128 * 32];   // fp32 staging, [row][32] (global_load_lds layout)
    __shared__ float Bs[128 * 32];

    const int tid  = threadIdx.x;
    const int wave = tid >> 6;
    const int lane = tid & 63;
    const int l15  = lane & 15;
    const int quad = lane >> 4;
    const int wm   = wave >> 1;
    const int wn   = wave & 1;
    const int m0   = blockIdx.y * 128;
    const int n0   = blockIdx.x * 128;

    floatx4 acc[4][4];
#pragma unroll
    for (int i = 0; i < 4; ++i)
#pragma unroll
        for (int j = 0; j < 4; ++j)
            acc[i][j] = (floatx4){0.f, 0.f, 0.f, 0.f};

    for (int kt = 0; kt < 32; ++kt) {
        const int k0 = kt * 32;
#pragma unroll
        for (int c = 0; c < 4; ++c) {
            const int base_e = (c * 4 + wave) * 256;   // floats; wave-uniform
            const int e   = base_e + lane * 4;         // this lane's 4 floats
            const int row = e >> 5;
            const int col = e & 31;
            const float* gA = X + (size_t)(m0 + row) * HD + k0 + col;
            const float* gB = W + (size_t)(n0 + row) * HD + k0 + col;
            __builtin_amdgcn_global_load_lds((gv_t*)gA, (lv_t*)(As + base_e), 16, 0, 0);
            __builtin_amdgcn_global_load_lds((gv_t*)gB, (lv_t*)(Bs + base_e), 16, 0, 0);
        }
        __syncthreads();   // vmcnt(0) drain before barrier

        bf16x8 af[4], bfr[4];
#pragma unroll
        for (int t = 0; t < 4; ++t) {
            af[t]  = cvt8(As + (wm * 64 + t * 16 + l15) * 32 + quad * 8);
            bfr[t] = cvt8(Bs + (wn * 64 + t * 16 + l15) * 32 + quad * 8);
        }
#pragma unroll
        for (int i = 0; i < 4; ++i)
#pragma unroll
            for (int j = 0; j < 4; ++j)
                acc[i][j] = __builtin_amdgcn_mfma_f32_16x16x32_bf16(
                    af[i], bfr[j], acc[i][j], 0, 0, 0);
        __syncthreads();
    }

    // Epilogue: bias + RoPE + scatter. C/D layout: col=lane&15, row=quad*4+reg.
    // ln(10000)/32 = 0.28782313662425572
#pragma unroll
    for (int i = 0; i < 4; ++i) {
        const int mrow_base = m0 + wm * 64 + i * 16 + quad * 4;
#pragma unroll
        for (int j = 0; j < 2; ++j) {
            const int n1 = n0 + wn * 64 + j * 16 + l15;    // dim in [0,32)
            const int n2 = n1 + 32;
            const float b1 = bias[n1];
            const float b2 = bias[n2];
            const int which = n1 >> 10;          // 0=q 1=k 2=v
            const int hd    = n1 & 1023;
            const int head  = hd >> 6;
            const int dim   = hd & 63;           // < 32 by construction
            const float inv_freq = expf(-(float)dim * 0.28782313662425572f);
            bf16_t* outp = (which == 0) ? qws : (which == 1) ? kws : vws;
#pragma unroll
            for (int r = 0; r < 4; ++r) {
                const int mrow = mrow_base + r;
                const int s    = mrow & (S_LEN - 1);
                const int bb   = mrow >> 11;
                float x1 = acc[i][j][r]     + b1;
                float x2 = acc[i][j + 2][r] + b2;
                float o1, o2;
                if (which < 2) {
                    const float ang = (float)s * inv_freq;
                    const float cs = cosf(ang);
                    const float sn = sinf(ang);
                    o1 = x1 * cs - x2 * sn;
                    o2 = x2 * cs + x1 * sn;
                } else {
                    o1 = x1; o2 = x2;
                }
                const size_t off = ((size_t)(bb * NHEAD + head) * S_LEN + s) * DHEAD + dim;
                outp[off]      = f2bf(o1);
                outp[off + 32] = f2bf(o2);
            }
        }
    }
}

// ---------------------------------------------------------------------------
// Kernel 2: flash attention per (bh, 64-row q-tile). 4 waves, 16 q-rows/wave.
// QK^T and PV via 16x16x32 bf16 MFMA; P round-trips LDS (C-layout -> A-layout).
// LDS rows padded to 72 elems (144 B): 2-way bank alias = free. fp32 out.
// ---------------------------------------------------------------------------
#define LDST 72

__global__ __launch_bounds__(256, 2)
void attn_kernel(const bf16_t* __restrict__ qws, const bf16_t* __restrict__ kws,
                 const bf16_t* __restrict__ vws, float* __restrict__ out)
{
    __shared__ bf16_t Qs[64 * LDST];
    __shared__ bf16_t Ks[64 * LDST];
    __shared__ bf16_t Vt[64 * LDST];   // transposed: [dim][t]
    __shared__ bf16_t Ps[64 * LDST];   // per-wave 16-row slabs

    const int tid  = threadIdx.x;
    const int wave = tid >> 6;
    const int lane = tid & 63;
    const int l15  = lane & 15;
    const int quad = lane >> 4;
    const int qt   = blockIdx.x;
    const int bh   = blockIdx.y;
    const size_t base = (size_t)bh * S_LEN * DHEAD;

    {
        const bf16_t* src = qws + base + (size_t)qt * 64 * DHEAD;
        const int row = tid >> 2;
        const int segbase = (tid & 3) * 8;
#pragma unroll
        for (int jj = 0; jj < 2; ++jj) {
            const int col = segbase + jj * 32;
            *(uint4*)(Qs + row * LDST + col) = *(const uint4*)(src + row * DHEAD + col);
        }
    }

    float m_i[4], l_i[4];
    floatx4 o_acc[4];
#pragma unroll
    for (int r = 0; r < 4; ++r) { m_i[r] = -1e30f; l_i[r] = 0.0f; }
#pragma unroll
    for (int t = 0; t < 4; ++t) o_acc[t] = (floatx4){0.f, 0.f, 0.f, 0.f};

    __syncthreads();

    for (int kt = 0; kt < 32; ++kt) {
        {
            const bf16_t* srcK = kws + base + (size_t)kt * 64 * DHEAD;
            const bf16_t* srcV = vws + base + (size_t)kt * 64 * DHEAD;
            const int row = tid >> 2;
            const int segbase = (tid & 3) * 8;
#pragma unroll
            for (int jj = 0; jj < 2; ++jj) {
                const int col = segbase + jj * 32;
                *(uint4*)(Ks + row * LDST + col) = *(const uint4*)(srcK + row * DHEAD + col);
                bf16_t vv[8];
                *(uint4*)vv = *(const uint4*)(srcV + row * DHEAD + col);
#pragma unroll
                for (int e = 0; e < 8; ++e)
                    Vt[(col + e) * LDST + row] = vv[e];
            }
        }
        __syncthreads();

        // S = (Q K^T) * 0.125 for this wave's 16 rows x 64 keys
        floatx4 sc[4];
#pragma unroll
        for (int nt = 0; nt < 4; ++nt) {
            floatx4 s4 = (floatx4){0.f, 0.f, 0.f, 0.f};
#pragma unroll
            for (int kb = 0; kb < 2; ++kb) {
                bf16x8 aq = *(const bf16x8*)(Qs + (wave * 16 + l15) * LDST + kb * 32 + quad * 8);
                bf16x8 bk = *(const bf16x8*)(Ks + (nt * 16 + l15) * LDST + kb * 32 + quad * 8);
                s4 = __builtin_amdgcn_mfma_f32_16x16x32_bf16(aq, bk, s4, 0, 0, 0);
            }
            sc[nt] = s4 * 0.125f;
        }

        // online softmax; lane's rows are quad*4 + r
        float mnew[4], alpha[4], rsum[4];
#pragma unroll
        for (int r = 0; r < 4; ++r) {
            float mx = fmaxf(fmaxf(sc[0][r], sc[1][r]), fmaxf(sc[2][r], sc[3][r]));
#pragma unroll
            for (int off = 1; off < 16; off <<= 1)
                mx = fmaxf(mx, __shfl_xor(mx, off, 64));
            mnew[r]  = fmaxf(m_i[r], mx);
            alpha[r] = __expf(m_i[r] - mnew[r]);
            rsum[r]  = 0.0f;
        }
#pragma unroll
        for (int nt = 0; nt < 4; ++nt) {
#pragma unroll
            for (int r = 0; r < 4; ++r) {
                const float p = __expf(sc[nt][r] - mnew[r]);
                const bf16_t pb = f2bf(p);
                rsum[r] += bf2f(pb);   // denominator consistent with bf16 P
                Ps[(wave * 16 + quad * 4 + r) * LDST + nt * 16 + l15] = pb;
            }
        }
#pragma unroll
        for (int r = 0; r < 4; ++r) {
            float sm = rsum[r];
#pragma unroll
            for (int off = 1; off < 16; off <<= 1)
                sm += __shfl_xor(sm, off, 64);
            l_i[r] = l_i[r] * alpha[r] + sm;
            m_i[r] = mnew[r];
        }
#pragma unroll
        for (int dt = 0; dt < 4; ++dt)
#pragma unroll
            for (int r = 0; r < 4; ++r)
                o_acc[dt][r] *= alpha[r];

        // O += P V
#pragma unroll
        for (int kb = 0; kb < 2; ++kb) {
            bf16x8 ap = *(const bf16x8*)(Ps + (wave * 16 + l15) * LDST + kb * 32 + quad * 8);
#pragma unroll
            for (int dt = 0; dt < 4; ++dt) {
                bf16x8 bv = *(const bf16x8*)(Vt + (dt * 16 + l15) * LDST + kb * 32 + quad * 8);
                o_acc[dt] = __builtin_amdgcn_mfma_f32_16x16x32_bf16(ap, bv, o_acc[dt], 0, 0, 0);
            }
        }
        __syncthreads();
    }

    // normalize + store out[b][s][h*64+dim] (fp32)
    const int bb = bh >> 4, hh = bh & 15;
#pragma unroll
    for (int r = 0; r < 4; ++r) {
        const float inv = 1.0f / l_i[r];
        const int s = qt * 64 + wave * 16 + quad * 4 + r;
        const size_t off0 = ((size_t)(bb * S_LEN + s)) * HD + hh * DHEAD;
#pragma unroll
        for (int dt = 0; dt < 4; ++dt)
            out[off0 + dt * 16 + l15] = o_acc[dt][r] * inv;
    }
}

extern "C" void kernel_launch(void* const* d_in, const int* in_sizes, int n_in,
                              void* d_out, int out_size, void* d_ws, size_t ws_size,
                              hipStream_t stream) {
    const float* X    = (const float*)d_in[0];   // (4,2048,1024) fp32
    const float* W    = (const float*)d_in[1];   // (3072,1024) fp32
    const float* bias = (const float*)d_in[2];   // (3072,) fp32
    float* out = (float*)d_out;                  // (4,2048,1024) fp32

    const size_t per = (size_t)B_SZ * NHEAD * S_LEN * DHEAD;   // 8.39M elems
    bf16_t* qws = (bf16_t*)d_ws;
    bf16_t* kws = qws + per;
    bf16_t* vws = kws + per;

    qkv_rope_kernel<<<dim3(N3 / 128, M_ROWS / 128), 256, 0, stream>>>(
        X, W, bias, qws, kws, vws);
    attn_kernel<<<dim3(S_LEN / 64, B_SZ * NHEAD), 256, 0, stream>>>(
        qws, kws, vws, out);
}

// Round 3
// 466.390 us; speedup vs baseline: 1.9036x; 1.9036x over previous
//
#include <hip/hip_runtime.h>
#include <hip/hip_bf16.h>
#include <math.h>

// Problem constants (B=4, S=2048, Hd=1024, h=16, d=64). fp32 in/out per the
// reference; bf16 internally (MFMA) with fp32 accumulation.
#define B_SZ   4
#define S_LEN  2048
#define HD     1024
#define NHEAD  16
#define DHEAD  64
#define N3     3072          // 3*Hd
#define M_ROWS 8192          // B*S

typedef __bf16 bf16_t;
typedef __bf16 bf16x8 __attribute__((ext_vector_type(8)));
typedef float  floatx4 __attribute__((ext_vector_type(4)));

__device__ __forceinline__ float bf2f(bf16_t x) { return (float)x; }
__device__ __forceinline__ bf16_t f2bf(float f) { return (bf16_t)f; }  // RNE fptrunc

__device__ __forceinline__ bf16x8 cvt8(const float4 lo, const float4 hi) {
    bf16x8 r;
    r[0] = (bf16_t)lo.x; r[1] = (bf16_t)lo.y; r[2] = (bf16_t)lo.z; r[3] = (bf16_t)lo.w;
    r[4] = (bf16_t)hi.x; r[5] = (bf16_t)hi.y; r[6] = (bf16_t)hi.z; r[7] = (bf16_t)hi.w;
    return r;
}

// ---------------------------------------------------------------------------
// Kernel 1: qkv = X @ W^T + b (fp32 in, bf16 MFMA, fp32 acc), fused RoPE on
// q,k; scatter bf16 to [b][h][s][d] workspace.
// 128x128 tile, BK=32, 2x2 waves, each wave 4x4 of 16x16x32 MFMA tiles.
// Staging: global fp32 float4-pairs -> in-register cvt to bf16 ->
// ds_write_b128 with block mapping b=half*256+tid (row=b>>2, colblk=b&3):
// each write instr spreads 64 lanes evenly over all 8 (parity x colblk) bank
// groups -> balanced 8-way (the m97 profile), killing the round-2 16-way
// fp32-row conflicts (2.74e8 conflict cycles = 79% of runtime).
// Register double-buffer: load kt+1 while computing kt.
// ---------------------------------------------------------------------------
__global__ __launch_bounds__(256, 3)
void qkv_rope_kernel(const float* __restrict__ X, const float* __restrict__ W,
                     const float* __restrict__ bias,
                     bf16_t* __restrict__ qws, bf16_t* __restrict__ kws,
                     bf16_t* __restrict__ vws)
{
    __shared__ bf16_t As[128 * 32];   // 8 KB, [row][32] bf16 (16-dword rows)
    __shared__ bf16_t Bs[128 * 32];   // 8 KB

    const int tid  = threadIdx.x;
    const int wave = tid >> 6;
    const int lane = tid & 63;
    const int l15  = lane & 15;
    const int quad = lane >> 4;
    const int wm   = wave >> 1;
    const int wn   = wave & 1;
    const int m0   = blockIdx.y * 128;
    const int n0   = blockIdx.x * 128;

    // block mapping for staging: two 8-elem blocks per thread per matrix
    const int b0   = tid;         // block 0..255
    const int b1   = tid + 256;   // block 256..511
    const int r0   = b0 >> 2, c0 = (b0 & 3) * 8;
    const int r1   = b1 >> 2, c1 = (b1 & 3) * 8;

    const float* gA0 = X + (size_t)(m0 + r0) * HD + c0;
    const float* gA1 = X + (size_t)(m0 + r1) * HD + c1;
    const float* gB0 = W + (size_t)(n0 + r0) * HD + c0;
    const float* gB1 = W + (size_t)(n0 + r1) * HD + c1;

    floatx4 acc[4][4];
#pragma unroll
    for (int i = 0; i < 4; ++i)
#pragma unroll
        for (int j = 0; j < 4; ++j)
            acc[i][j] = (floatx4){0.f, 0.f, 0.f, 0.f};

    // preload kt=0
    float4 a0l = *(const float4*)(gA0);     float4 a0h = *(const float4*)(gA0 + 4);
    float4 a1l = *(const float4*)(gA1);     float4 a1h = *(const float4*)(gA1 + 4);
    float4 w0l = *(const float4*)(gB0);     float4 w0h = *(const float4*)(gB0 + 4);
    float4 w1l = *(const float4*)(gB1);     float4 w1h = *(const float4*)(gB1 + 4);

    for (int kt = 0; kt < 32; ++kt) {
        // write staged regs -> LDS (bf16)
        *(bf16x8*)(As + r0 * 32 + c0) = cvt8(a0l, a0h);
        *(bf16x8*)(As + r1 * 32 + c1) = cvt8(a1l, a1h);
        *(bf16x8*)(Bs + r0 * 32 + c0) = cvt8(w0l, w0h);
        *(bf16x8*)(Bs + r1 * 32 + c1) = cvt8(w1l, w1h);
        __syncthreads();

        // issue next k-tile's global loads (overlap with MFMA below)
        if (kt + 1 < 32) {
            const int k0 = (kt + 1) * 32;
            a0l = *(const float4*)(gA0 + k0);  a0h = *(const float4*)(gA0 + k0 + 4);
            a1l = *(const float4*)(gA1 + k0);  a1h = *(const float4*)(gA1 + k0 + 4);
            w0l = *(const float4*)(gB0 + k0);  w0h = *(const float4*)(gB0 + k0 + 4);
            w1l = *(const float4*)(gB1 + k0);  w1h = *(const float4*)(gB1 + k0 + 4);
        }

        bf16x8 af[4], bfr[4];
#pragma unroll
        for (int t = 0; t < 4; ++t) {
            af[t]  = *(const bf16x8*)(As + (wm * 64 + t * 16 + l15) * 32 + quad * 8);
            bfr[t] = *(const bf16x8*)(Bs + (wn * 64 + t * 16 + l15) * 32 + quad * 8);
        }
#pragma unroll
        for (int i = 0; i < 4; ++i)
#pragma unroll
            for (int j = 0; j < 4; ++j)
                acc[i][j] = __builtin_amdgcn_mfma_f32_16x16x32_bf16(
                    af[i], bfr[j], acc[i][j], 0, 0, 0);
        __syncthreads();
    }

    // Epilogue: bias + RoPE + scatter. C/D layout: col=lane&15, row=quad*4+reg.
    // ln(10000)/32 = 0.28782313662425572
#pragma unroll
    for (int i = 0; i < 4; ++i) {
        const int mrow_base = m0 + wm * 64 + i * 16 + quad * 4;
#pragma unroll
        for (int j = 0; j < 2; ++j) {
            const int n1 = n0 + wn * 64 + j * 16 + l15;    // dim in [0,32)
            const int n2 = n1 + 32;
            const float b1 = bias[n1];
            const float b2 = bias[n2];
            const int which = n1 >> 10;          // 0=q 1=k 2=v
            const int hd    = n1 & 1023;
            const int head  = hd >> 6;
            const int dim   = hd & 63;           // < 32 by construction
            const float inv_freq = expf(-(float)dim * 0.28782313662425572f);
            bf16_t* outp = (which == 0) ? qws : (which == 1) ? kws : vws;
#pragma unroll
            for (int r = 0; r < 4; ++r) {
                const int mrow = mrow_base + r;
                const int s    = mrow & (S_LEN - 1);
                const int bb   = mrow >> 11;
                float x1 = acc[i][j][r]     + b1;
                float x2 = acc[i][j + 2][r] + b2;
                float o1, o2;
                if (which < 2) {
                    const float ang = (float)s * inv_freq;
                    const float cs = cosf(ang);
                    const float sn = sinf(ang);
                    o1 = x1 * cs - x2 * sn;
                    o2 = x2 * cs + x1 * sn;
                } else {
                    o1 = x1; o2 = x2;
                }
                const size_t off = ((size_t)(bb * NHEAD + head) * S_LEN + s) * DHEAD + dim;
                outp[off]      = f2bf(o1);
                outp[off + 32] = f2bf(o2);
            }
        }
    }
}

// ---------------------------------------------------------------------------
// Kernel 2: flash attention per (bh, 64-row q-tile). 4 waves, 16 q-rows/wave.
// QK^T and PV via 16x16x32 bf16 MFMA; P round-trips LDS (C-layout -> A-layout).
// LDS rows padded to 72 elems (144 B): 2-way bank alias = free. fp32 out.
// (unchanged from round 2 to isolate the kernel-1 fix)
// ---------------------------------------------------------------------------
#define LDST 72

__global__ __launch_bounds__(256, 2)
void attn_kernel(const bf16_t* __restrict__ qws, const bf16_t* __restrict__ kws,
                 const bf16_t* __restrict__ vws, float* __restrict__ out)
{
    __shared__ bf16_t Qs[64 * LDST];
    __shared__ bf16_t Ks[64 * LDST];
    __shared__ bf16_t Vt[64 * LDST];   // transposed: [dim][t]
    __shared__ bf16_t Ps[64 * LDST];   // per-wave 16-row slabs

    const int tid  = threadIdx.x;
    const int wave = tid >> 6;
    const int lane = tid & 63;
    const int l15  = lane & 15;
    const int quad = lane >> 4;
    const int qt   = blockIdx.x;
    const int bh   = blockIdx.y;
    const size_t base = (size_t)bh * S_LEN * DHEAD;

    {
        const bf16_t* src = qws + base + (size_t)qt * 64 * DHEAD;
        const int row = tid >> 2;
        const int segbase = (tid & 3) * 8;
#pragma unroll
        for (int jj = 0; jj < 2; ++jj) {
            const int col = segbase + jj * 32;
            *(uint4*)(Qs + row * LDST + col) = *(const uint4*)(src + row * DHEAD + col);
        }
    }

    float m_i[4], l_i[4];
    floatx4 o_acc[4];
#pragma unroll
    for (int r = 0; r < 4; ++r) { m_i[r] = -1e30f; l_i[r] = 0.0f; }
#pragma unroll
    for (int t = 0; t < 4; ++t) o_acc[t] = (floatx4){0.f, 0.f, 0.f, 0.f};

    __syncthreads();

    for (int kt = 0; kt < 32; ++kt) {
        {
            const bf16_t* srcK = kws + base + (size_t)kt * 64 * DHEAD;
            const bf16_t* srcV = vws + base + (size_t)kt * 64 * DHEAD;
            const int row = tid >> 2;
            const int segbase = (tid & 3) * 8;
#pragma unroll
            for (int jj = 0; jj < 2; ++jj) {
                const int col = segbase + jj * 32;
                *(uint4*)(Ks + row * LDST + col) = *(const uint4*)(srcK + row * DHEAD + col);
                bf16_t vv[8];
                *(uint4*)vv = *(const uint4*)(srcV + row * DHEAD + col);
#pragma unroll
                for (int e = 0; e < 8; ++e)
                    Vt[(col + e) * LDST + row] = vv[e];
            }
        }
        __syncthreads();

        // S = (Q K^T) * 0.125 for this wave's 16 rows x 64 keys
        floatx4 sc[4];
#pragma unroll
        for (int nt = 0; nt < 4; ++nt) {
            floatx4 s4 = (floatx4){0.f, 0.f, 0.f, 0.f};
#pragma unroll
            for (int kb = 0; kb < 2; ++kb) {
                bf16x8 aq = *(const bf16x8*)(Qs + (wave * 16 + l15) * LDST + kb * 32 + quad * 8);
                bf16x8 bk = *(const bf16x8*)(Ks + (nt * 16 + l15) * LDST + kb * 32 + quad * 8);
                s4 = __builtin_amdgcn_mfma_f32_16x16x32_bf16(aq, bk, s4, 0, 0, 0);
            }
            sc[nt] = s4 * 0.125f;
        }

        // online softmax; lane's rows are quad*4 + r
        float mnew[4], alpha[4], rsum[4];
#pragma unroll
        for (int r = 0; r < 4; ++r) {
            float mx = fmaxf(fmaxf(sc[0][r], sc[1][r]), fmaxf(sc[2][r], sc[3][r]));
#pragma unroll
            for (int off = 1; off < 16; off <<= 1)
                mx = fmaxf(mx, __shfl_xor(mx, off, 64));
            mnew[r]  = fmaxf(m_i[r], mx);
            alpha[r] = __expf(m_i[r] - mnew[r]);
            rsum[r]  = 0.0f;
        }
#pragma unroll
        for (int nt = 0; nt < 4; ++nt) {
#pragma unroll
            for (int r = 0; r < 4; ++r) {
                const float p = __expf(sc[nt][r] - mnew[r]);
                const bf16_t pb = f2bf(p);
                rsum[r] += bf2f(pb);   // denominator consistent with bf16 P
                Ps[(wave * 16 + quad * 4 + r) * LDST + nt * 16 + l15] = pb;
            }
        }
#pragma unroll
        for (int r = 0; r < 4; ++r) {
            float sm = rsum[r];
#pragma unroll
            for (int off = 1; off < 16; off <<= 1)
                sm += __shfl_xor(sm, off, 64);
            l_i[r] = l_i[r] * alpha[r] + sm;
            m_i[r] = mnew[r];
        }
#pragma unroll
        for (int dt = 0; dt < 4; ++dt)
#pragma unroll
            for (int r = 0; r < 4; ++r)
                o_acc[dt][r] *= alpha[r];

        // O += P V
#pragma unroll
        for (int kb = 0; kb < 2; ++kb) {
            bf16x8 ap = *(const bf16x8*)(Ps + (wave * 16 + l15) * LDST + kb * 32 + quad * 8);
#pragma unroll
            for (int dt = 0; dt < 4; ++dt) {
                bf16x8 bv = *(const bf16x8*)(Vt + (dt * 16 + l15) * LDST + kb * 32 + quad * 8);
                o_acc[dt] = __builtin_amdgcn_mfma_f32_16x16x32_bf16(ap, bv, o_acc[dt], 0, 0, 0);
            }
        }
        __syncthreads();
    }

    // normalize + store out[b][s][h*64+dim] (fp32)
    const int bb = bh >> 4, hh = bh & 15;
#pragma unroll
    for (int r = 0; r < 4; ++r) {
        const float inv = 1.0f / l_i[r];
        const int s = qt * 64 + wave * 16 + quad * 4 + r;
        const size_t off0 = ((size_t)(bb * S_LEN + s)) * HD + hh * DHEAD;
#pragma unroll
        for (int dt = 0; dt < 4; ++dt)
            out[off0 + dt * 16 + l15] = o_acc[dt][r] * inv;
    }
}

extern "C" void kernel_launch(void* const* d_in, const int* in_sizes, int n_in,
                              void* d_out, int out_size, void* d_ws, size_t ws_size,
                              hipStream_t stream) {
    const float* X    = (const float*)d_in[0];   // (4,2048,1024) fp32
    const float* W    = (const float*)d_in[1];   // (3072,1024) fp32
    const float* bias = (const float*)d_in[2];   // (3072,) fp32
    float* out = (float*)d_out;                  // (4,2048,1024) fp32

    const size_t per = (size_t)B_SZ * NHEAD * S_LEN * DHEAD;   // 8.39M elems
    bf16_t* qws = (bf16_t*)d_ws;
    bf16_t* kws = qws + per;
    bf16_t* vws = kws + per;

    qkv_rope_kernel<<<dim3(N3 / 128, M_ROWS / 128), 256, 0, stream>>>(
        X, W, bias, qws, kws, vws);
    attn_kernel<<<dim3(S_LEN / 64, B_SZ * NHEAD), 256, 0, stream>>>(
        qws, kws, vws, out);
}